// Round 8
// baseline (111.504 us; speedup 1.0000x reference)
//
#include <hip/hip_runtime.h>

#define N2 16384
#define N1 65536

// ---- output layout (float offsets) ----
#define OUT_AIM 7225344         // 21*21*N2
#define OUT_LD  14450688        // 2*21*21*N2
#define OUT_ZRE 14450689
#define OUT_ZIM 14794753        // OUT_ZRE + 21*N2

// ---- LDS layout (float offsets), TILE_J = 64 ----
// T2 rows padded to stride 72 floats (288 B: keeps 16 B alignment for
// ds_read_b128, rotates banks by 8 dwords/row so the 4 different q-rows a
// wave reads in one b128 land on different bank groups).
#define T2STR  72
#define L_T2R  0                // [20][72]
#define L_T2I  1440             // [20][72]
#define L_M2   2880             // [c:2][u:4][64]
#define L_SC   3392             // [idx:26][u:4][64]
//   idx 0..3  t1r[b], 4..7  t1i[b], 8..11 p1r[b], 12..15 p1i[b],
//   idx 16..19 i0r[k], 20..23 i0i[k], 24 is1r, 25 is1i
#define L_IS2R 10048            // [64]
#define L_IS2I 10112            // [64]
#define L_RED  10176            // [7]
#define L_TOT  10184            // ~40.7 KB

#define SC(idx, u, jl) lds[L_SC + (((idx)*4 + (u)) * 64) + (jl)]
#define SCOFF(idx, u)  (L_SC + (((idx)*4 + (u)) * 64))
#define LDSF4(off)     (*reinterpret_cast<const float4*>(&lds[(off)]))

// 16-byte packed store of 4 adjacent floats (global_store_dwordx4)
#define ST4(addr, a0, a1, a2, a3) do {                                        \
    float4 _o; _o.x=(a0); _o.y=(a1); _o.z=(a2); _o.w=(a3);                    \
    *reinterpret_cast<float4*>(addr) = _o; } while (0)

// ---- workspace: 256 doubles (per-block logdet partials), reduced by the
// tiny finalize dispatch (stream-ordered; kernel-boundary release/acquire).

// ---- phase-2 per-row-slot machinery (3 rows per wave-group) ----
// Lane = (h: q mod 4, ci: column quad). Each lane owns 4 adjacent columns
// -> every A store is a 16 B dwordx4 (halves store-instruction count vs the
// 8 B variant; R6 showed fused is store-issue-limited at ~9 cyc/store).
// All arrays are constant-indexed after unroll -> stay in registers.
#define SLOT_PREP(s, P)                                                       \
    const int  p##s = (P);                                                    \
    const bool is20_##s = (p##s == 20);                                       \
    const int  ap_##s = p##s >> 2, up_##s = p##s & 3;                         \
    const bool sc_##s = (!is20_##s) && (h == up_##s);                         \
    float ppr_##s[4], ppi_##s[4], par_##s[4], pai_##s[4];                     \
    float zar_##s[4] = {0.f,0.f,0.f,0.f}, zai_##s[4] = {0.f,0.f,0.f,0.f};     \
    _Pragma("unroll") for (int j = 0; j < 4; ++j) {                           \
        ppr_##s[j]=0.f; ppi_##s[j]=0.f; par_##s[j]=0.f; pai_##s[j]=0.f; }     \
    if (!is20_##s) {                                                          \
        const float4 tr4 = LDSF4(L_T2R + p##s*T2STR + c4);                    \
        const float4 ti4 = LDSF4(L_T2I + p##s*T2STR + c4);                    \
        const float tpr[4] = {tr4.x, tr4.y, tr4.z, tr4.w};                    \
        const float tpi[4] = {ti4.x, ti4.y, ti4.z, ti4.w};                    \
        _Pragma("unroll") for (int j = 0; j < 4; ++j) {                       \
            ppr_##s[j] = tpr[j]*is2r[j] - tpi[j]*is2i[j];                     \
            ppi_##s[j] = tpr[j]*is2i[j] + tpi[j]*is2r[j]; }                   \
        if (ap_##s < 4) {                                                     \
            const float4 pr4 = LDSF4(SCOFF(8+ap_##s,  up_##s) + c4);          \
            const float4 pi4 = LDSF4(SCOFF(12+ap_##s, up_##s) + c4);          \
            par_##s[0]=pr4.x; par_##s[1]=pr4.y; par_##s[2]=pr4.z; par_##s[3]=pr4.w; \
            pai_##s[0]=pi4.x; pai_##s[1]=pi4.y; pai_##s[2]=pi4.z; pai_##s[3]=pi4.w; \
        }                                                                     \
    }

// main q rows: q = 4*qi + h < 20 (qi = 0..4). Scatter b = qi when h == up.
#define SLOT_QMAIN(s) do {                                                    \
    float ar[4], ai[4];                                                       \
    if (is20_##s) {                                                           \
        _Pragma("unroll") for (int j = 0; j < 4; ++j) {                       \
            ar[j] = -(tq[j]*is2r[j] - uq[j]*is2i[j]);                         \
            ai[j] =   tq[j]*is2i[j] + uq[j]*is2r[j]; }                        \
    } else {                                                                  \
        _Pragma("unroll") for (int j = 0; j < 4; ++j) {                       \
            ar[j] = ppr_##s[j]*tq[j] + ppi_##s[j]*uq[j];                      \
            ai[j] = ppi_##s[j]*tq[j] - ppr_##s[j]*uq[j]; }                    \
        if (sc_##s) {                                                         \
            if (ap_##s < 4) {                                                 \
                if (qi < 4) {                                                 \
                    const float4 br4 = LDSF4(SCOFF(qi,   up_##s) + c4);       \
                    const float4 bi4 = LDSF4(SCOFF(4+qi, up_##s) + c4);       \
                    const float tb[4] = {br4.x, br4.y, br4.z, br4.w};         \
                    const float ub[4] = {bi4.x, bi4.y, bi4.z, bi4.w};         \
                    _Pragma("unroll") for (int j = 0; j < 4; ++j) {           \
                        ar[j] += par_##s[j]*tb[j] + pai_##s[j]*ub[j];         \
                        ai[j] += pai_##s[j]*tb[j] - par_##s[j]*ub[j]; }       \
                    if (qi == ap_##s) {        /* + 1/lam00 */                \
                        const float4 ir4 = LDSF4(SCOFF(16+ap_##s, up_##s) + c4); \
                        const float4 ii4 = LDSF4(SCOFF(20+ap_##s, up_##s) + c4); \
                        ar[0]+=ir4.x; ar[1]+=ir4.y; ar[2]+=ir4.z; ar[3]+=ir4.w; \
                        ai[0]+=ii4.x; ai[1]+=ii4.y; ai[2]+=ii4.z; ai[3]+=ii4.w; \
                    }                                                         \
                } else {                       /* b==4: -P1[ap] */            \
                    _Pragma("unroll") for (int j = 0; j < 4; ++j) {           \
                        ar[j] -= par_##s[j]; ai[j] -= pai_##s[j]; }           \
                }                                                             \
            } else {                                                          \
                if (qi < 4) {                  /* -conj(P1[b]) */             \
                    const float4 pr4 = LDSF4(SCOFF(8+qi,  up_##s) + c4);      \
                    const float4 pi4 = LDSF4(SCOFF(12+qi, up_##s) + c4);      \
                    ar[0]-=pr4.x; ar[1]-=pr4.y; ar[2]-=pr4.z; ar[3]-=pr4.w;   \
                    ai[0]+=pi4.x; ai[1]+=pi4.y; ai[2]+=pi4.z; ai[3]+=pi4.w;   \
                } else {                       /* 1/S1 */                     \
                    const float4 sr4 = LDSF4(SCOFF(24, up_##s) + c4);         \
                    const float4 si4 = LDSF4(SCOFF(25, up_##s) + c4);         \
                    ar[0]+=sr4.x; ar[1]+=sr4.y; ar[2]+=sr4.z; ar[3]+=sr4.w;   \
                    ai[0]+=si4.x; ai[1]+=si4.y; ai[2]+=si4.z; ai[3]+=si4.w;   \
                }                                                             \
            }                                                                 \
        }                                                                     \
    }                                                                         \
    ST4(out + (p##s*21+q)*N2 + j4,           ar[0], ar[1], ar[2], ar[3]);     \
    ST4(out + OUT_AIM + (p##s*21+q)*N2 + j4, ai[0], ai[1], ai[2], ai[3]);     \
    _Pragma("unroll") for (int j = 0; j < 4; ++j) {                           \
        zar_##s[j] += zq[j]*ar[j] - wq[j]*ai[j];                              \
        zai_##s[j] += zq[j]*ai[j] + wq[j]*ar[j]; }                            \
} while (0)

// tail q == 20 (h==0 lanes only)
#define SLOT_QTAIL(s) do {                                                    \
    float ar[4], ai[4];                                                       \
    _Pragma("unroll") for (int j = 0; j < 4; ++j) {                           \
        if (is20_##s) { ar[j] = is2r[j];       ai[j] = is2i[j]; }             \
        else          { ar[j] = -ppr_##s[j];   ai[j] = -ppi_##s[j]; } }       \
    ST4(out + (p##s*21+20)*N2 + j4,           ar[0], ar[1], ar[2], ar[3]);    \
    ST4(out + OUT_AIM + (p##s*21+20)*N2 + j4, ai[0], ai[1], ai[2], ai[3]);    \
    _Pragma("unroll") for (int j = 0; j < 4; ++j) {                           \
        zar_##s[j] += zq[j]*ar[j] - wq[j]*ai[j];                              \
        zai_##s[j] += zq[j]*ai[j] + wq[j]*ar[j]; }                            \
} while (0)

// reduce z across the 4 h-groups, redistribute to 1 col/lane, coalesced store
#define SLOT_ZFIN(s) do {                                                     \
    _Pragma("unroll") for (int j = 0; j < 4; ++j) {                           \
        zar_##s[j] += __shfl_xor(zar_##s[j], 16, 64);                         \
        zar_##s[j] += __shfl_xor(zar_##s[j], 32, 64);                         \
        zai_##s[j] += __shfl_xor(zai_##s[j], 16, 64);                         \
        zai_##s[j] += __shfl_xor(zai_##s[j], 32, 64); }                       \
    const int srcl = l >> 2;                                                  \
    const float ra = __shfl(zar_##s[0], srcl, 64);                            \
    const float rb = __shfl(zar_##s[1], srcl, 64);                            \
    const float rc = __shfl(zar_##s[2], srcl, 64);                            \
    const float rd = __shfl(zar_##s[3], srcl, 64);                            \
    const float ia = __shfl(zai_##s[0], srcl, 64);                            \
    const float ib = __shfl(zai_##s[1], srcl, 64);                            \
    const float ic = __shfl(zai_##s[2], srcl, 64);                            \
    const float id = __shfl(zai_##s[3], srcl, 64);                            \
    const int sel = l & 3;                                                    \
    const float zvr = sel==0 ? ra : sel==1 ? rb : sel==2 ? rc : rd;           \
    const float zvi = sel==0 ? ia : sel==1 ? ib : sel==2 ? ic : id;           \
    out[OUT_ZRE + p##s*N2 + j0 + l] = zvr;                                    \
    out[OUT_ZIM + p##s*N2 + j0 + l] = zvi;                                    \
} while (0)

// grid = (N2/64, 1), block = 448 threads (7 waves).
// Phase 1 (Schur chain) once per column tile; phase 2's wave-group g emits
// output rows p = g, g+7, g+14 in one fused q-loop. Lane layout in phase 2:
// h = lane>>4 owns q ≡ h (mod 4); ci = lane&15 owns 4 adjacent columns ->
// all A stores are dwordx4 (1 KB per wave store instruction).
__global__ __launch_bounds__(448) void fused_kernel(
    const float* __restrict__ l00r, const float* __restrict__ l00i,
    const float* __restrict__ l01r, const float* __restrict__ l01i,
    const float* __restrict__ l02r, const float* __restrict__ l02i,
    const float* __restrict__ l11r, const float* __restrict__ l11i,
    const float* __restrict__ l12r, const float* __restrict__ l12i,
    const float* __restrict__ l22r, const float* __restrict__ l22i,
    const float* __restrict__ zre,  const float* __restrict__ zim,
    float* __restrict__ out, double* __restrict__ ld_partial)
{
    __shared__ float lds[L_TOT];
    const int t   = threadIdx.x;
    const int jl  = t & 63;
    const int j0  = blockIdx.x * 64;
    float ld = 0.f;

    // ================= phase 1: stage 0/1/2 per (u, jl) =================
    if (t < 256) {
        const int u = t >> 6;
        const int m = u * N2 + (j0 + jl);

        float i0r[4], i0i[4], t1r[4], t1i[4], p1r[4], p1i[4];
        float m1r = 0.f, m1i = 0.f;
#pragma unroll
        for (int k = 0; k < 4; ++k) {
            const int i = k * N1 + m;
            const float ar = l00r[i], ai = l00i[i];
            const float br = l01r[i], bi = l01i[i];
            const float d  = ar*ar + ai*ai;
            const float rd = 1.f / d;
            ld += 0.5f * logf(d);                   // log|lam00|
            const float xr = ar * rd, xi = -ai * rd;
            i0r[k] = xr; i0i[k] = xi;
            const float tr = br*xr - bi*xi;         // T1 = lam01/lam00
            const float ti = br*xi + bi*xr;
            t1r[k] = tr; t1i[k] = ti;
            m1r += br*tr + bi*ti;                   // conj(lam01)*T1
            m1i += br*ti - bi*tr;
        }
        const float s1r = l11r[m] - m1r;
        const float s1i = l11i[m] - m1i;
        const float ds1 = s1r*s1r + s1i*s1i;
        ld += 0.5f * logf(ds1);                     // log|S1|
        const float rds1 = 1.f / ds1;
        const float is1r = s1r * rds1, is1i = -s1i * rds1;
#pragma unroll
        for (int k = 0; k < 4; ++k) {
            p1r[k] = t1r[k]*is1r - t1i[k]*is1i;     // P1 = T1/S1
            p1i[k] = t1r[k]*is1i + t1i[k]*is1r;
        }

        // stage-2 B column: Bcol[a<4]=lam02[a*N1+m], Bcol[4]=lam12[m]
        float bcr[5], bci[5];
#pragma unroll
        for (int a = 0; a < 4; ++a) { bcr[a] = l02r[a*N1+m]; bci[a] = l02i[a*N1+m]; }
        bcr[4] = l12r[m]; bci[4] = l12i[m];

        // W = sum_{b<4} Bcol[b]*conj(T1[b]) - Bcol[4]
        float wr = -bcr[4], wi = -bci[4];
#pragma unroll
        for (int b = 0; b < 4; ++b) {
            wr += bcr[b]*t1r[b] + bci[b]*t1i[b];
            wi += bci[b]*t1r[b] - bcr[b]*t1i[b];
        }
        // T2 rows q = a*4+u
        float ur[5], ui[5];
#pragma unroll
        for (int a = 0; a < 4; ++a) {
            ur[a] = p1r[a]*wr - p1i[a]*wi + bcr[a]*i0r[a] - bci[a]*i0i[a];
            ui[a] = p1r[a]*wi + p1i[a]*wr + bcr[a]*i0i[a] + bci[a]*i0r[a];
        }
        {
            float vr = bcr[4]*is1r - bci[4]*is1i;   // Bcol[4]/S1
            float vi = bcr[4]*is1i + bci[4]*is1r;
#pragma unroll
            for (int b = 0; b < 4; ++b) {           // - Bcol[b]*conj(P1[b])
                vr -= bcr[b]*p1r[b] + bci[b]*p1i[b];
                vi -= bci[b]*p1r[b] - bcr[b]*p1i[b];
            }
            ur[4] = vr; ui[4] = vi;
        }
        float m2r = 0.f, m2i = 0.f;
#pragma unroll
        for (int a = 0; a < 5; ++a) {
            lds[L_T2R + (a*4+u)*T2STR + jl] = ur[a];
            lds[L_T2I + (a*4+u)*T2STR + jl] = ui[a];
            m2r += bcr[a]*ur[a] + bci[a]*ui[a];     // conj(B)*T2
            m2i += bcr[a]*ui[a] - bci[a]*ur[a];
        }
        lds[L_M2 + (0*4+u)*64 + jl] = m2r;
        lds[L_M2 + (1*4+u)*64 + jl] = m2i;
#pragma unroll
        for (int b = 0; b < 4; ++b) {
            SC(b,      u, jl) = t1r[b];  SC(4+b,  u, jl) = t1i[b];
            SC(8+b,    u, jl) = p1r[b];  SC(12+b, u, jl) = p1i[b];
            SC(16+b,   u, jl) = i0r[b];  SC(20+b, u, jl) = i0i[b];
        }
        SC(24, u, jl) = is1r;  SC(25, u, jl) = is1i;
    }
    __syncthreads();

    // ================= phase 1.5: S2 per column =================
    if (t < 64) {
        float s2r = l22r[j0 + t], s2i = l22i[j0 + t];
#pragma unroll
        for (int u = 0; u < 4; ++u) {
            s2r -= lds[L_M2 + (0*4+u)*64 + t];
            s2i -= lds[L_M2 + (1*4+u)*64 + t];
        }
        const float ds2  = s2r*s2r + s2i*s2i;
        const float rds2 = 1.f / ds2;
        lds[L_IS2R + t] =  s2r * rds2;
        lds[L_IS2I + t] = -s2i * rds2;
        ld += 0.5f * logf(ds2);                     // log|S2|
    }
    __syncthreads();

    // ===== phase 2: rows p = g, g+7, g+14; lane = (h: q mod 4, ci: col quad) =====
    const int g  = t >> 6;                          // wave group 0..6
    const int l  = t & 63;
    const int h  = l >> 4;                          // q ≡ h (mod 4)
    const int ci = l & 15;                          // column-quad index
    const int c4 = 4*ci;
    const int j4 = j0 + c4;                         // first of the 4 columns

    const float4 _r4 = LDSF4(L_IS2R + c4);
    const float4 _i4 = LDSF4(L_IS2I + c4);
    const float is2r[4] = {_r4.x, _r4.y, _r4.z, _r4.w};
    const float is2i[4] = {_i4.x, _i4.y, _i4.z, _i4.w};

    SLOT_PREP(0, g)
    SLOT_PREP(1, g + 7)
    SLOT_PREP(2, g + 14)

#pragma unroll
    for (int qi = 0; qi < 5; ++qi) {
        const int q = 4*qi + h;                     // < 20 always
        const float4 t4 = LDSF4(L_T2R + q*T2STR + c4);
        const float4 u4 = LDSF4(L_T2I + q*T2STR + c4);
        const float tq[4] = {t4.x, t4.y, t4.z, t4.w};
        const float uq[4] = {u4.x, u4.y, u4.z, u4.w};
        const float4 z4 = *reinterpret_cast<const float4*>(zre + q*N2 + j4);
        const float4 w4 = *reinterpret_cast<const float4*>(zim + q*N2 + j4);
        const float zq[4] = {z4.x, z4.y, z4.z, z4.w};
        const float wq[4] = {w4.x, w4.y, w4.z, w4.w};
        SLOT_QMAIN(0);
        SLOT_QMAIN(1);
        SLOT_QMAIN(2);
    }

    if (h == 0) {                                   // tail row q == 20
        const float4 z4 = *reinterpret_cast<const float4*>(zre + 20*N2 + j4);
        const float4 w4 = *reinterpret_cast<const float4*>(zim + 20*N2 + j4);
        const float zq[4] = {z4.x, z4.y, z4.z, z4.w};
        const float wq[4] = {w4.x, w4.y, w4.z, w4.w};
        SLOT_QTAIL(0);
        SLOT_QTAIL(1);
        SLOT_QTAIL(2);
    }

    SLOT_ZFIN(0);
    SLOT_ZFIN(1);
    SLOT_ZFIN(2);

    // ================= logdet block reduction -> ws partial =================
    {
        float v = ld;
#pragma unroll
        for (int off = 32; off > 0; off >>= 1) v += __shfl_down(v, off, 64);
        __syncthreads();                            // LDS reuse guard
        if (jl == 0) lds[L_RED + g] = v;
        __syncthreads();
        if (t == 0) {
            double s = 0.0;
#pragma unroll
            for (int w = 0; w < 7; ++w) s += (double)lds[L_RED + w];
            ld_partial[blockIdx.x] = s;
        }
    }
}

// 1 block, 256 threads: reduce the 256 double partials, write OUT_LD.
__global__ __launch_bounds__(256) void finalize_kernel(
    const double* __restrict__ part, float* __restrict__ out)
{
    double v = part[threadIdx.x];
#pragma unroll
    for (int off = 32; off > 0; off >>= 1) v += __shfl_down(v, off, 64);
    __shared__ double wsum[4];
    if ((threadIdx.x & 63) == 0) wsum[threadIdx.x >> 6] = v;
    __syncthreads();
    if (threadIdx.x == 0)
        out[OUT_LD] = (float)(wsum[0] + wsum[1] + wsum[2] + wsum[3]);
}

extern "C" void kernel_launch(void* const* d_in, const int* in_sizes, int n_in,
                              void* d_out, int out_size, void* d_ws, size_t ws_size,
                              hipStream_t stream)
{
    const float* l00r = (const float*)d_in[0];
    const float* l00i = (const float*)d_in[1];
    const float* l01r = (const float*)d_in[2];
    const float* l01i = (const float*)d_in[3];
    const float* l02r = (const float*)d_in[4];
    const float* l02i = (const float*)d_in[5];
    const float* l11r = (const float*)d_in[6];
    const float* l11i = (const float*)d_in[7];
    const float* l12r = (const float*)d_in[8];
    const float* l12i = (const float*)d_in[9];
    const float* l22r = (const float*)d_in[10];
    const float* l22i = (const float*)d_in[11];
    const float* zre  = (const float*)d_in[12];
    const float* zim  = (const float*)d_in[13];
    float*  out        = (float*)d_out;
    double* ld_partial = (double*)d_ws;             // 256 doubles, rewritten each call

    fused_kernel<<<dim3(N2/64, 1), dim3(448), 0, stream>>>(
        l00r,l00i,l01r,l01i,l02r,l02i,l11r,l11i,l12r,l12i,l22r,l22i,
        zre,zim, out, ld_partial);
    finalize_kernel<<<1, 256, 0, stream>>>(ld_partial, out);
}